// Round 3
// baseline (146.557 us; speedup 1.0000x reference)
//
#include <hip/hip_runtime.h>
#include <stdint.h>

#define NWL 31

typedef __attribute__((ext_vector_type(8))) short short8;
typedef __attribute__((ext_vector_type(4))) short short4v;
typedef __attribute__((ext_vector_type(4))) float f32x4;

#define WCOMP 32768                 // bytes per (layer, hi-or-lo) fragment block
#define WLAYER 65536                // hi+lo per layer
#define WS_W_BYTES (NWL * WLAYER)   // 2,031,616 B

#define LDS_WBUF0 0
#define LDS_WBUF1 65536
#define LDS_ACTH  131072
#define LDS_ACTL  147456
#define LDS_TOTAL 163840            // exactly 160 KiB

__device__ __forceinline__ uint16_t f2bf(float f) {
  uint32_t u = __builtin_bit_cast(uint32_t, f);
  u += 0x7FFFu + ((u >> 16) & 1u);            // RNE
  return (uint16_t)(u >> 16);
}
__device__ __forceinline__ float bf2f(uint16_t b) {
  return __builtin_bit_cast(float, (uint32_t)b << 16);
}

__device__ __forceinline__ void gload_lds16(const void* g, void* l) {
  __builtin_amdgcn_global_load_lds(
      (const __attribute__((address_space(1))) uint32_t*)g,
      (__attribute__((address_space(3))) uint32_t*)l, 16, 0, 0);
}

// ---------------------------------------------------------------------------
// Prep: WM = W*M  ->  MFMA-fragment-ordered bf16 hi/lo in ws, plus f32 bias.
// Fragment order per layer/comp: [kk(4)][ntile(8)][lane(64)][8 bf16] (16B/lane)
// where the lane holds B[k = kk*32 + 8*(lane>>4) + i][n = ntile*16 + (lane&15)].
// ---------------------------------------------------------------------------
__global__ __launch_bounds__(512)
void prep_weights(const float* __restrict__ W, const float* __restrict__ M,
                  char* __restrict__ wsW, float* __restrict__ wsB) {
  const int l    = blockIdx.x >> 2;
  const int kk   = blockIdx.x & 3;
  const int nt   = threadIdx.x >> 6;
  const int lane = threadIdx.x & 63;
  const int kbase = kk * 32 + ((lane >> 4) << 3);
  const int n     = (nt << 4) + (lane & 15);
  const float* Wl = W + l * 129 * 128;
  const float* Ml = M + l * 129 * 128;
  short8 vh, vl;
#pragma unroll
  for (int i = 0; i < 8; ++i) {
    const int k = kbase + i;
    const float v = Wl[k * 128 + n] * Ml[k * 128 + n];
    const uint16_t h = f2bf(v);
    vh[i] = (short)h;
    vl[i] = (short)f2bf(v - bf2f(h));
  }
  char* base = wsW + l * WLAYER;
  const int frag = ((kk * 8 + nt) * 64 + lane) * 16;
  *(short8*)(base + frag)         = vh;
  *(short8*)(base + WCOMP + frag) = vl;
  if (kk == 0 && threadIdx.x < 128) {
    const int t = threadIdx.x;
    wsB[l * 128 + t] = Wl[128 * 128 + t] * Ml[128 * 128 + t];
  }
}

// ---------------------------------------------------------------------------
// Main: 256 blocks x 512 threads. 8 waves split 2M x 4N (wave tile 32x32,
// acc[2][2]) -- minimizes LDS re-reads: A*4 + B*2 = 256 KiB/layer vs 320 KiB
// for the 4Mx2N split (LDS pipe ~2048 cyc vs MFMA ~1860 cyc: balanced).
// Block owns 64 batch rows for all 31 layers. act in LDS as hi/lo bf16,
// XOR-swizzled granules (granule ^= row&7) -> A-reads hit the minimum 8
// bank-phases. Weights double-buffered via global_load_lds, prefetch 1 layer
// ahead. acc init = bias; 3-term hi/lo split MFMA; epilogue relu + re-split.
// ---------------------------------------------------------------------------
__global__ __launch_bounds__(512, 2)
void dag_mlp(const float* __restrict__ x, const char* __restrict__ wsW,
             const float* __restrict__ wsB, float* __restrict__ out) {
  extern __shared__ char lds[];
  const int tid  = threadIdx.x;
  const int lane = tid & 63;
  const int wv   = tid >> 6;   // wave 0..7
  const int wm   = wv >> 2;    // M-half 0..1 (32 rows)
  const int wn   = wv & 3;     // N-quarter 0..3 (32 cols)
  const int l16  = lane & 15;
  const int g4   = lane >> 4;
  const int r0   = blockIdx.x << 6;

  // ---- async: layer-0 weights -> LDS buf0
  {
    const char* g = wsW;
#pragma unroll
    for (int r = 0; r < 8; ++r) {
      const int off = r * 8192 + wv * 1024;
      gload_lds16(g + off + lane * 16, lds + LDS_WBUF0 + off);
    }
  }
  // ---- x -> act hi/lo (swizzled), float4-vectorized
#pragma unroll
  for (int it = 0; it < 4; ++it) {
    const int idx = tid + it * 512;       // float4 index in [64][32]
    const int row = idx >> 5;
    const int k4  = idx & 31;
    const f32x4 v = *(const f32x4*)(x + (size_t)(r0 + row) * 128 + k4 * 4);
    short4v hv, lv;
#pragma unroll
    for (int c = 0; c < 4; ++c) {
      const uint16_t h = f2bf(v[c]);
      hv[c] = (short)h;
      lv[c] = (short)f2bf(v[c] - bf2f(h));
    }
    const int off = row * 256 + (((k4 >> 1) ^ (row & 7)) << 4) + ((k4 & 1) << 3);
    *(short4v*)(lds + LDS_ACTH + off) = hv;
    *(short4v*)(lds + LDS_ACTL + off) = lv;
  }
  __syncthreads();

  f32x4 acc[2][2];

  for (int l = 0; l < NWL; ++l) {
    const int cur = l & 1;
    // prefetch next layer's weights into the other buffer
    if (l + 1 < NWL) {
      const char* g = wsW + (size_t)(l + 1) * WLAYER;
      const int dstbase = cur ? LDS_WBUF0 : LDS_WBUF1;
#pragma unroll
      for (int r = 0; r < 8; ++r) {
        const int off = r * 8192 + wv * 1024;
        gload_lds16(g + off + lane * 16, lds + dstbase + off);
      }
    }
    // bias -> accumulator init (C/D col = lane&15)
#pragma unroll
    for (int fc = 0; fc < 2; ++fc) {
      const float bv = wsB[l * 128 + wn * 32 + fc * 16 + l16];
      f32x4 t = {bv, bv, bv, bv};
      acc[0][fc] = t;
      acc[1][fc] = t;
    }
    // A fragments: row = wm*32 + fr*16 + l16, k = kk*32 + g4*8 + i
    short8 aH[2][4], aL[2][4];
#pragma unroll
    for (int fr = 0; fr < 2; ++fr) {
      const int arow = wm * 32 + fr * 16 + l16;
#pragma unroll
      for (int kk = 0; kk < 4; ++kk) {
        const int off = arow * 256 + ((((kk << 2) + g4) ^ (arow & 7)) << 4);
        aH[fr][kk] = *(const short8*)(lds + LDS_ACTH + off);
        aL[fr][kk] = *(const short8*)(lds + LDS_ACTL + off);
      }
    }
    const int wbase = cur ? LDS_WBUF1 : LDS_WBUF0;
#pragma unroll
    for (int kk = 0; kk < 4; ++kk) {
      short8 bH[2], bL[2];
#pragma unroll
      for (int fc = 0; fc < 2; ++fc) {
        const int foff = wbase + (((kk * 8 + wn * 2 + fc) * 64 + lane) << 4);
        bH[fc] = *(const short8*)(lds + foff);
        bL[fc] = *(const short8*)(lds + WCOMP + foff);
      }
#pragma unroll
      for (int fr = 0; fr < 2; ++fr)
#pragma unroll
        for (int fc = 0; fc < 2; ++fc)
          acc[fr][fc] = __builtin_amdgcn_mfma_f32_16x16x32_bf16(aH[fr][kk], bH[fc], acc[fr][fc], 0, 0, 0);
#pragma unroll
      for (int fr = 0; fr < 2; ++fr)
#pragma unroll
        for (int fc = 0; fc < 2; ++fc)
          acc[fr][fc] = __builtin_amdgcn_mfma_f32_16x16x32_bf16(aL[fr][kk], bH[fc], acc[fr][fc], 0, 0, 0);
#pragma unroll
      for (int fr = 0; fr < 2; ++fr)
#pragma unroll
        for (int fc = 0; fc < 2; ++fc)
          acc[fr][fc] = __builtin_amdgcn_mfma_f32_16x16x32_bf16(aH[fr][kk], bL[fc], acc[fr][fc], 0, 0, 0);
    }
    __syncthreads();   // all waves done reading act + weights (also drains prefetch)
    if (l == NWL - 1) {
#pragma unroll
      for (int fr = 0; fr < 2; ++fr)
#pragma unroll
        for (int fc = 0; fc < 2; ++fc) {
          const int col = wn * 32 + fc * 16 + l16;
#pragma unroll
          for (int i = 0; i < 4; ++i) {
            const int row = r0 + wm * 32 + fr * 16 + g4 * 4 + i;
            out[(size_t)row * 128 + col] = fmaxf(acc[fr][fc][i], 0.0f);
          }
        }
    } else {
#pragma unroll
      for (int fr = 0; fr < 2; ++fr)
#pragma unroll
        for (int fc = 0; fc < 2; ++fc) {
          const int col = wn * 32 + fc * 16 + l16;   // feature index of output
#pragma unroll
          for (int i = 0; i < 4; ++i) {
            const int row = wm * 32 + fr * 16 + g4 * 4 + i;
            const float v = fmaxf(acc[fr][fc][i], 0.0f);
            const uint16_t h  = f2bf(v);
            const uint16_t lo = f2bf(v - bf2f(h));
            const int off = row * 256 + (((col >> 3) ^ (row & 7)) << 4) + ((col & 7) << 1);
            *(uint16_t*)(lds + LDS_ACTH + off) = h;
            *(uint16_t*)(lds + LDS_ACTL + off) = lo;
          }
        }
      __syncthreads();  // act writes visible before next layer's A reads
    }
  }
}

// ---------------------------------------------------------------------------
extern "C" void kernel_launch(void* const* d_in, const int* in_sizes, int n_in,
                              void* d_out, int out_size, void* d_ws, size_t ws_size,
                              hipStream_t stream) {
  const float* x = (const float*)d_in[0];
  const float* W = (const float*)d_in[1];
  const float* M = (const float*)d_in[2];
  char*  wsW = (char*)d_ws;
  float* wsB = (float*)((char*)d_ws + WS_W_BYTES);
  float* out = (float*)d_out;

  (void)hipFuncSetAttribute((const void*)dag_mlp,
                            hipFuncAttributeMaxDynamicSharedMemorySize, LDS_TOTAL);

  hipLaunchKernelGGL(prep_weights, dim3(NWL * 4), dim3(512), 0, stream, W, M, wsW, wsB);
  hipLaunchKernelGGL(dag_mlp, dim3(256), dim3(512), LDS_TOTAL, stream, x, wsW, wsB, out);
}

// Round 4
// 130.197 us; speedup vs baseline: 1.1257x; 1.1257x over previous
//
#include <hip/hip_runtime.h>
#include <stdint.h>

#define NWL 31

typedef __attribute__((ext_vector_type(8))) short short8;
typedef __attribute__((ext_vector_type(4))) float f32x4;
typedef __attribute__((ext_vector_type(4))) uint32_t u32x4;

#define WCOMP 32768                 // bytes per (layer, hi-or-lo) fragment block
#define WLAYER 65536                // hi+lo per layer
#define WS_W_BYTES (NWL * WLAYER)   // 2,031,616 B

#define LDS_WBUF0 0                 // [H 32K | L 32K]
#define LDS_WBUF1 65536
#define LDS_ACT   131072            // packed u32 act: 64 rows x 512 B
#define LDS_TOTAL 163840            // exactly 160 KiB

__device__ __forceinline__ uint16_t f2bf(float f) {
  uint32_t u = __builtin_bit_cast(uint32_t, f);
  u += 0x7FFFu + ((u >> 16) & 1u);            // RNE (prep only)
  return (uint16_t)(u >> 16);
}
__device__ __forceinline__ float bf2f(uint16_t b) {
  return __builtin_bit_cast(float, (uint32_t)b << 16);
}

// byte-permute helpers: result = {hi[31:16], lo[31:16]} / {hi[15:0], lo[15:0]}
__device__ __forceinline__ uint32_t perm_hihi(uint32_t hi, uint32_t lo) {
#if __has_builtin(__builtin_amdgcn_perm)
  return __builtin_amdgcn_perm(hi, lo, 0x07060302u);
#else
  return (hi & 0xFFFF0000u) | (lo >> 16);
#endif
}
__device__ __forceinline__ uint32_t perm_lolo(uint32_t hi, uint32_t lo) {
#if __has_builtin(__builtin_amdgcn_perm)
  return __builtin_amdgcn_perm(hi, lo, 0x05040100u);
#else
  return (hi << 16) | (lo & 0xFFFFu);
#endif
}

__device__ __forceinline__ void gload_lds16(const void* g, void* l) {
  __builtin_amdgcn_global_load_lds(
      (const __attribute__((address_space(1))) uint32_t*)g,
      (__attribute__((address_space(3))) uint32_t*)l, 16, 0, 0);
}

// ---------------------------------------------------------------------------
// Prep (unchanged layout): WM = W*M -> MFMA-fragment-ordered bf16 hi/lo in ws,
// plus f32 bias. Lane holds B[k=kk*32+8*(lane>>4)+i][n=ntile*16+(lane&15)].
// ---------------------------------------------------------------------------
__global__ __launch_bounds__(512)
void prep_weights(const float* __restrict__ W, const float* __restrict__ M,
                  char* __restrict__ wsW, float* __restrict__ wsB) {
  const int l    = blockIdx.x >> 2;
  const int kk   = blockIdx.x & 3;
  const int nt   = threadIdx.x >> 6;
  const int lane = threadIdx.x & 63;
  const int kbase = kk * 32 + ((lane >> 4) << 3);
  const int n     = (nt << 4) + (lane & 15);
  const float* Wl = W + l * 129 * 128;
  const float* Ml = M + l * 129 * 128;
  short8 vh, vl;
#pragma unroll
  for (int i = 0; i < 8; ++i) {
    const int k = kbase + i;
    const float v = Wl[k * 128 + n] * Ml[k * 128 + n];
    const uint16_t h = f2bf(v);
    vh[i] = (short)h;
    vl[i] = (short)f2bf(v - bf2f(h));
  }
  char* base = wsW + l * WLAYER;
  const int frag = ((kk * 8 + nt) * 64 + lane) * 16;
  *(short8*)(base + frag)         = vh;
  *(short8*)(base + WCOMP + frag) = vl;
  if (kk == 0 && threadIdx.x < 128) {
    const int t = threadIdx.x;
    wsB[l * 128 + t] = Wl[128 * 128 + t] * Ml[128 * 128 + t];
  }
}

// ---------------------------------------------------------------------------
// Main: 256 blocks x 512 threads, 8 waves 2M x 4N (wave tile 32x32, acc[2][2]).
// Act in LDS as PACKED u32 (lo_bf16<<16 | hi_bf16), XOR-swizzled 16B granules
// -> epilogue is one conflict-free ds_write_b32/elem; A-frags deinterleaved
// with v_perm. All LDS offsets layer-invariant, precomputed into VGPRs.
// Weights double-buffered via global_load_lds (prefetch 1 layer ahead).
// acc=0 init; bias added in epilogue (L2 latency covered by whole layer).
// ---------------------------------------------------------------------------
__global__ __launch_bounds__(512, 2)
void dag_mlp(const float* __restrict__ x, const char* __restrict__ wsW,
             const float* __restrict__ wsB, float* __restrict__ out) {
  extern __shared__ char lds[];
  const int tid  = threadIdx.x;
  const int lane = tid & 63;
  const int wv   = tid >> 6;   // wave 0..7
  const int wm   = wv >> 2;    // M-half (32 rows)
  const int wn   = wv & 3;     // N-quarter (32 cols)
  const int l16  = lane & 15;
  const int g4   = lane >> 4;
  const int r0   = blockIdx.x << 6;

  // ---- async: layer-0 weights -> LDS buf0
#pragma unroll
  for (int r = 0; r < 8; ++r) {
    const int off = r * 8192 + wv * 1024;
    gload_lds16(wsW + off + lane * 16, lds + LDS_WBUF0 + off);
  }

  // ---- x -> packed act (swizzled), one b128 write per 4 cols
#pragma unroll
  for (int it = 0; it < 4; ++it) {
    const int idx = tid + it * 512;       // [64 rows][32 col-quads]
    const int row = idx >> 5;
    const int cq  = idx & 31;
    const f32x4 v = *(const f32x4*)(x + (size_t)(r0 + row) * 128 + cq * 4);
    u32x4 w;
#pragma unroll
    for (int c = 0; c < 4; ++c) {
      const uint32_t u  = __builtin_bit_cast(uint32_t, v[c]);
      const float    hi = __builtin_bit_cast(float, u & 0xFFFF0000u);
      const uint32_t ur = __builtin_bit_cast(uint32_t, v[c] - hi);
      w[c] = perm_hihi(ur, u);            // lo16=hi_bf16, hi16=lo_bf16
    }
    const int off = row * 512 + ((cq ^ (row & 7)) << 4);
    *(u32x4*)(lds + LDS_ACT + off) = w;
  }

  // ---- layer-invariant LDS offsets (live in VGPRs across the whole loop)
  int aoff[2][4][2];                      // A granule-pair reads
#pragma unroll
  for (int fr = 0; fr < 2; ++fr) {
    const int arow = wm * 32 + fr * 16 + l16;
#pragma unroll
    for (int kk = 0; kk < 4; ++kk) {
      const int g0 = kk * 8 + g4 * 2;
      aoff[fr][kk][0] = arow * 512 + (((g0    ) ^ (arow & 7)) << 4);
      aoff[fr][kk][1] = arow * 512 + (((g0 + 1) ^ (arow & 7)) << 4);
    }
  }
  int boff[4][2];                         // B fragment reads (buf0-H base)
#pragma unroll
  for (int kk = 0; kk < 4; ++kk)
#pragma unroll
    for (int fc = 0; fc < 2; ++fc)
      boff[kk][fc] = (((kk * 8 + wn * 2 + fc) * 64 + lane) << 4);
  int eoff[2][2][4];                      // epilogue packed-u32 writes
#pragma unroll
  for (int fr = 0; fr < 2; ++fr)
#pragma unroll
    for (int fc = 0; fc < 2; ++fc) {
      const int col = wn * 32 + fc * 16 + l16;
#pragma unroll
      for (int i = 0; i < 4; ++i) {
        const int row = wm * 32 + fr * 16 + g4 * 4 + i;
        eoff[fr][fc][i] = row * 512 + (((col >> 2) ^ (row & 7)) << 4) + ((col & 3) << 2);
      }
    }
  const float* biasp = wsB + wn * 32 + l16;

  __syncthreads();

  int wsel = 0;                           // 0 / 65536: current weight buffer
  for (int l = 0; l < NWL; ++l) {
    // prefetch next layer's weights into the other buffer
    if (l + 1 < NWL) {
      const char* g = wsW + (size_t)(l + 1) * WLAYER;
      const int dst = wsel ^ 65536;
#pragma unroll
      for (int r = 0; r < 8; ++r) {
        const int off = r * 8192 + wv * 1024;
        gload_lds16(g + off + lane * 16, lds + dst + off);
      }
    }
    // bias loads issued early, consumed at epilogue
    const float bias0 = biasp[l * 128];
    const float bias1 = biasp[l * 128 + 16];

    // A fragments: read packed granule pairs, deinterleave via perm
    u32x4 ah[2][4], al[2][4];
#pragma unroll
    for (int fr = 0; fr < 2; ++fr)
#pragma unroll
      for (int kk = 0; kk < 4; ++kk) {
        const u32x4 p0 = *(const u32x4*)(lds + LDS_ACT + aoff[fr][kk][0]);
        const u32x4 p1 = *(const u32x4*)(lds + LDS_ACT + aoff[fr][kk][1]);
        ah[fr][kk][0] = perm_lolo(p0[1], p0[0]);
        ah[fr][kk][1] = perm_lolo(p0[3], p0[2]);
        ah[fr][kk][2] = perm_lolo(p1[1], p1[0]);
        ah[fr][kk][3] = perm_lolo(p1[3], p1[2]);
        al[fr][kk][0] = perm_hihi(p0[1], p0[0]);
        al[fr][kk][1] = perm_hihi(p0[3], p0[2]);
        al[fr][kk][2] = perm_hihi(p1[1], p1[0]);
        al[fr][kk][3] = perm_hihi(p1[3], p1[2]);
      }

    f32x4 acc[2][2];
#pragma unroll
    for (int fr = 0; fr < 2; ++fr)
#pragma unroll
      for (int fc = 0; fc < 2; ++fc) {
        f32x4 z = {0.f, 0.f, 0.f, 0.f};
        acc[fr][fc] = z;
      }

#pragma unroll
    for (int kk = 0; kk < 4; ++kk) {
      short8 bH[2], bL[2];
#pragma unroll
      for (int fc = 0; fc < 2; ++fc) {
        const char* p = lds + wsel + boff[kk][fc];
        bH[fc] = *(const short8*)(p);
        bL[fc] = *(const short8*)(p + WCOMP);
      }
#pragma unroll
      for (int fr = 0; fr < 2; ++fr) {
        const short8 aH = __builtin_bit_cast(short8, ah[fr][kk]);
#pragma unroll
        for (int fc = 0; fc < 2; ++fc)
          acc[fr][fc] = __builtin_amdgcn_mfma_f32_16x16x32_bf16(aH, bH[fc], acc[fr][fc], 0, 0, 0);
      }
#pragma unroll
      for (int fr = 0; fr < 2; ++fr) {
        const short8 aL = __builtin_bit_cast(short8, al[fr][kk]);
#pragma unroll
        for (int fc = 0; fc < 2; ++fc)
          acc[fr][fc] = __builtin_amdgcn_mfma_f32_16x16x32_bf16(aL, bH[fc], acc[fr][fc], 0, 0, 0);
      }
#pragma unroll
      for (int fr = 0; fr < 2; ++fr) {
        const short8 aH = __builtin_bit_cast(short8, ah[fr][kk]);
#pragma unroll
        for (int fc = 0; fc < 2; ++fc)
          acc[fr][fc] = __builtin_amdgcn_mfma_f32_16x16x32_bf16(aH, bL[fc], acc[fr][fc], 0, 0, 0);
      }
    }

    __syncthreads();   // all waves done reading act+weights (drains prefetch)

    if (l == NWL - 1) {
#pragma unroll
      for (int fr = 0; fr < 2; ++fr)
#pragma unroll
        for (int fc = 0; fc < 2; ++fc) {
          const float bias = fc ? bias1 : bias0;
          const int col = wn * 32 + fc * 16 + l16;
#pragma unroll
          for (int i = 0; i < 4; ++i) {
            const int row = r0 + wm * 32 + fr * 16 + g4 * 4 + i;
            out[(size_t)row * 128 + col] = fmaxf(acc[fr][fc][i] + bias, 0.0f);
          }
        }
    } else {
#pragma unroll
      for (int fr = 0; fr < 2; ++fr)
#pragma unroll
        for (int fc = 0; fc < 2; ++fc) {
          const float bias = fc ? bias1 : bias0;
#pragma unroll
          for (int i = 0; i < 4; ++i) {
            const float v = fmaxf(acc[fr][fc][i] + bias, 0.0f);
            const uint32_t u  = __builtin_bit_cast(uint32_t, v);
            const float    hi = __builtin_bit_cast(float, u & 0xFFFF0000u);
            const uint32_t ur = __builtin_bit_cast(uint32_t, v - hi);
            *(uint32_t*)(lds + LDS_ACT + eoff[fr][fc][i]) = perm_hihi(ur, u);
          }
        }
      __syncthreads();  // act writes visible before next layer's A reads
      wsel ^= 65536;
    }
  }
}

// ---------------------------------------------------------------------------
extern "C" void kernel_launch(void* const* d_in, const int* in_sizes, int n_in,
                              void* d_out, int out_size, void* d_ws, size_t ws_size,
                              hipStream_t stream) {
  const float* x = (const float*)d_in[0];
  const float* W = (const float*)d_in[1];
  const float* M = (const float*)d_in[2];
  char*  wsW = (char*)d_ws;
  float* wsB = (float*)((char*)d_ws + WS_W_BYTES);
  float* out = (float*)d_out;

  (void)hipFuncSetAttribute((const void*)dag_mlp,
                            hipFuncAttributeMaxDynamicSharedMemorySize, LDS_TOTAL);

  hipLaunchKernelGGL(prep_weights, dim3(NWL * 4), dim3(512), 0, stream, W, M, wsW, wsB);
  hipLaunchKernelGGL(dag_mlp, dim3(256), dim3(512), LDS_TOTAL, stream, x, wsW, wsB, out);
}

// Round 7
// 124.595 us; speedup vs baseline: 1.1763x; 1.0450x over previous
//
#include <hip/hip_runtime.h>
#include <stdint.h>

#define NWL 31

typedef __attribute__((ext_vector_type(8))) short short8;
typedef __attribute__((ext_vector_type(4))) float f32x4;
typedef __attribute__((ext_vector_type(4))) uint32_t u32x4;

#define WCOMP 32768                 // bytes per (layer, hi-or-lo) fragment block
#define WLAYER 65536                // hi+lo per layer
#define WS_W_BYTES (NWL * WLAYER)   // 2,031,616 B

#define LDS_ACT0 0                  // packed u32 act ping: 64 rows x 512 B
#define LDS_ACT1 32768              // pong
#define LDS_TOTAL 65536

__device__ __forceinline__ uint16_t f2bf(float f) {
  uint32_t u = __builtin_bit_cast(uint32_t, f);
  u += 0x7FFFu + ((u >> 16) & 1u);            // RNE (prep only)
  return (uint16_t)(u >> 16);
}
__device__ __forceinline__ float bf2f(uint16_t b) {
  return __builtin_bit_cast(float, (uint32_t)b << 16);
}

// byte-permute helpers: result = {hi[31:16], lo[31:16]} / {hi[15:0], lo[15:0]}
__device__ __forceinline__ uint32_t perm_hihi(uint32_t hi, uint32_t lo) {
#if __has_builtin(__builtin_amdgcn_perm)
  return __builtin_amdgcn_perm(hi, lo, 0x07060302u);
#else
  return (hi & 0xFFFF0000u) | (lo >> 16);
#endif
}
__device__ __forceinline__ uint32_t perm_lolo(uint32_t hi, uint32_t lo) {
#if __has_builtin(__builtin_amdgcn_perm)
  return __builtin_amdgcn_perm(hi, lo, 0x05040100u);
#else
  return (hi << 16) | (lo & 0xFFFFu);
#endif
}

// ---------------------------------------------------------------------------
// Prep (unchanged): WM = W*M -> MFMA-fragment-ordered bf16 hi/lo in ws, plus
// f32 bias. Lane holds B[k=kk*32+8*(lane>>4)+i][n=ntile*16+(lane&15)].
// ---------------------------------------------------------------------------
__global__ __launch_bounds__(512)
void prep_weights(const float* __restrict__ W, const float* __restrict__ M,
                  char* __restrict__ wsW, float* __restrict__ wsB) {
  const int l    = blockIdx.x >> 2;
  const int kk   = blockIdx.x & 3;
  const int nt   = threadIdx.x >> 6;
  const int lane = threadIdx.x & 63;
  const int kbase = kk * 32 + ((lane >> 4) << 3);
  const int n     = (nt << 4) + (lane & 15);
  const float* Wl = W + l * 129 * 128;
  const float* Ml = M + l * 129 * 128;
  short8 vh, vl;
#pragma unroll
  for (int i = 0; i < 8; ++i) {
    const int k = kbase + i;
    const float v = Wl[k * 128 + n] * Ml[k * 128 + n];
    const uint16_t h = f2bf(v);
    vh[i] = (short)h;
    vl[i] = (short)f2bf(v - bf2f(h));
  }
  char* base = wsW + l * WLAYER;
  const int frag = ((kk * 8 + nt) * 64 + lane) * 16;
  *(short8*)(base + frag)         = vh;
  *(short8*)(base + WCOMP + frag) = vl;
  if (kk == 0 && threadIdx.x < 128) {
    const int t = threadIdx.x;
    wsB[l * 128 + t] = Wl[128 * 128 + t] * Ml[128 * 128 + t];
  }
}

// ---------------------------------------------------------------------------
// Main: 256 blocks x 512 threads, 8 waves 2M x 4N (wave tile 32x32, acc[2][2]).
// B (weights) stream GLOBAL->VGPR, double-buffered one layer ahead (no LDS for
// B, no DMA staging): removes ~2000 cyc/layer from the LDS pipe, which R4's
// counters showed ~73% busy. Act packed u32 (lo<<16|hi), PING-PONG in LDS ->
// ONE barrier per layer. A-frags deinterleaved via v_perm; offsets
// layer-invariant in VGPRs; B reg arrays compile-time-indexed (macro-unrolled
// 2-layer parity).
// ---------------------------------------------------------------------------
__global__ __launch_bounds__(512, 2)
void dag_mlp(const float* __restrict__ x, const char* __restrict__ wsW,
             const float* __restrict__ wsB, float* __restrict__ out) {
  extern __shared__ char lds[];
  const int tid  = threadIdx.x;
  const int lane = tid & 63;
  const int wv   = tid >> 6;   // wave 0..7
  const int wm   = wv >> 2;    // M-half (32 rows)
  const int wn   = wv & 3;     // N-quarter (32 cols)
  const int l16  = lane & 15;
  const int g4   = lane >> 4;
  const int r0   = blockIdx.x << 6;

  // ---- x -> packed act ping (swizzled), one b128 write per 4 cols
#pragma unroll
  for (int it = 0; it < 4; ++it) {
    const int idx = tid + it * 512;       // [64 rows][32 col-quads]
    const int row = idx >> 5;
    const int cq  = idx & 31;
    const f32x4 v = *(const f32x4*)(x + (size_t)(r0 + row) * 128 + cq * 4);
    u32x4 w;
#pragma unroll
    for (int c = 0; c < 4; ++c) {
      const uint32_t u  = __builtin_bit_cast(uint32_t, v[c]);
      const float    hi = __builtin_bit_cast(float, u & 0xFFFF0000u);
      const uint32_t ur = __builtin_bit_cast(uint32_t, v[c] - hi);
      w[c] = perm_hihi(ur, u);            // lo16=hi_bf16, hi16=lo_bf16
    }
    const int off = row * 512 + ((cq ^ (row & 7)) << 4);
    *(u32x4*)(lds + LDS_ACT0 + off) = w;
  }

  // ---- layer-invariant offsets
  int aoff[2][4][2];                      // A granule-pair reads (act-relative)
#pragma unroll
  for (int fr = 0; fr < 2; ++fr) {
    const int arow = wm * 32 + fr * 16 + l16;
#pragma unroll
    for (int kk = 0; kk < 4; ++kk) {
      const int g0 = kk * 8 + g4 * 2;
      aoff[fr][kk][0] = arow * 512 + (((g0    ) ^ (arow & 7)) << 4);
      aoff[fr][kk][1] = arow * 512 + (((g0 + 1) ^ (arow & 7)) << 4);
    }
  }
  int eoff[2][2][4];                      // epilogue packed-u32 writes
#pragma unroll
  for (int fr = 0; fr < 2; ++fr)
#pragma unroll
    for (int fc = 0; fc < 2; ++fc) {
      const int col = wn * 32 + fc * 16 + l16;
#pragma unroll
      for (int i = 0; i < 4; ++i) {
        const int row = wm * 32 + fr * 16 + g4 * 4 + i;
        eoff[fr][fc][i] = row * 512 + (((col >> 2) ^ (row & 7)) << 4) + ((col & 3) << 2);
      }
    }
  const float* biasL = wsB + wn * 32 + l16;
  const char*  wlane = wsW + wn * 2048 + (size_t)lane * 16;  // B frag base

  // ---- preload layer-0 B into registers
  u32x4 B0[16], B1[16];
#pragma unroll
  for (int kk = 0; kk < 4; ++kk)
#pragma unroll
    for (int fc = 0; fc < 2; ++fc)
#pragma unroll
      for (int hl = 0; hl < 2; ++hl)
        B0[kk * 4 + fc * 2 + hl] =
            *(const u32x4*)(wlane + kk * 8192 + fc * 1024 + hl * 32768);

  __syncthreads();                        // act ping visible

#define LAYER_BODY(l, Bc, Bn, RDB, WRB, LAST, PREF)                            \
  do {                                                                         \
    if (PREF) {                                                                \
      const char* wl = wlane + (size_t)((l) + 1) * WLAYER;                     \
      _Pragma("unroll") for (int kk = 0; kk < 4; ++kk)                         \
      _Pragma("unroll") for (int fc = 0; fc < 2; ++fc)                         \
      _Pragma("unroll") for (int hl = 0; hl < 2; ++hl)                         \
        (Bn)[kk * 4 + fc * 2 + hl] =                                           \
            *(const u32x4*)(wl + kk * 8192 + fc * 1024 + hl * 32768);          \
    }                                                                          \
    const float bias0 = biasL[(l) * 128];                                      \
    const float bias1 = biasL[(l) * 128 + 16];                                 \
    f32x4 acc[2][2];                                                           \
    _Pragma("unroll") for (int fr = 0; fr < 2; ++fr)                           \
    _Pragma("unroll") for (int fc = 0; fc < 2; ++fc) {                         \
      f32x4 z = {0.f, 0.f, 0.f, 0.f};                                          \
      acc[fr][fc] = z;                                                         \
    }                                                                          \
    _Pragma("unroll") for (int kk = 0; kk < 4; ++kk) {                         \
      const u32x4 p00 = *(const u32x4*)(lds + (RDB) + aoff[0][kk][0]);         \
      const u32x4 p01 = *(const u32x4*)(lds + (RDB) + aoff[0][kk][1]);         \
      const u32x4 p10 = *(const u32x4*)(lds + (RDB) + aoff[1][kk][0]);         \
      const u32x4 p11 = *(const u32x4*)(lds + (RDB) + aoff[1][kk][1]);         \
      u32x4 h0, l0, h1, l1;                                                    \
      h0[0] = perm_lolo(p00[1], p00[0]);  h0[1] = perm_lolo(p00[3], p00[2]);   \
      h0[2] = perm_lolo(p01[1], p01[0]);  h0[3] = perm_lolo(p01[3], p01[2]);   \
      l0[0] = perm_hihi(p00[1], p00[0]);  l0[1] = perm_hihi(p00[3], p00[2]);   \
      l0[2] = perm_hihi(p01[1], p01[0]);  l0[3] = perm_hihi(p01[3], p01[2]);   \
      h1[0] = perm_lolo(p10[1], p10[0]);  h1[1] = perm_lolo(p10[3], p10[2]);   \
      h1[2] = perm_lolo(p11[1], p11[0]);  h1[3] = perm_lolo(p11[3], p11[2]);   \
      l1[0] = perm_hihi(p10[1], p10[0]);  l1[1] = perm_hihi(p10[3], p10[2]);   \
      l1[2] = perm_hihi(p11[1], p11[0]);  l1[3] = perm_hihi(p11[3], p11[2]);   \
      const short8 a0H = __builtin_bit_cast(short8, h0);                       \
      const short8 a0L = __builtin_bit_cast(short8, l0);                       \
      const short8 a1H = __builtin_bit_cast(short8, h1);                       \
      const short8 a1L = __builtin_bit_cast(short8, l1);                       \
      const short8 bH0 = __builtin_bit_cast(short8, (Bc)[kk * 4 + 0]);         \
      const short8 bL0 = __builtin_bit_cast(short8, (Bc)[kk * 4 + 1]);         \
      const short8 bH1 = __builtin_bit_cast(short8, (Bc)[kk * 4 + 2]);         \
      const short8 bL1 = __builtin_bit_cast(short8, (Bc)[kk * 4 + 3]);         \
      acc[0][0] = __builtin_amdgcn_mfma_f32_16x16x32_bf16(a0H, bH0, acc[0][0], 0, 0, 0); \
      acc[0][1] = __builtin_amdgcn_mfma_f32_16x16x32_bf16(a0H, bH1, acc[0][1], 0, 0, 0); \
      acc[1][0] = __builtin_amdgcn_mfma_f32_16x16x32_bf16(a1H, bH0, acc[1][0], 0, 0, 0); \
      acc[1][1] = __builtin_amdgcn_mfma_f32_16x16x32_bf16(a1H, bH1, acc[1][1], 0, 0, 0); \
      acc[0][0] = __builtin_amdgcn_mfma_f32_16x16x32_bf16(a0L, bH0, acc[0][0], 0, 0, 0); \
      acc[0][1] = __builtin_amdgcn_mfma_f32_16x16x32_bf16(a0L, bH1, acc[0][1], 0, 0, 0); \
      acc[1][0] = __builtin_amdgcn_mfma_f32_16x16x32_bf16(a1L, bH0, acc[1][0], 0, 0, 0); \
      acc[1][1] = __builtin_amdgcn_mfma_f32_16x16x32_bf16(a1L, bH1, acc[1][1], 0, 0, 0); \
      acc[0][0] = __builtin_amdgcn_mfma_f32_16x16x32_bf16(a0H, bL0, acc[0][0], 0, 0, 0); \
      acc[0][1] = __builtin_amdgcn_mfma_f32_16x16x32_bf16(a0H, bL1, acc[0][1], 0, 0, 0); \
      acc[1][0] = __builtin_amdgcn_mfma_f32_16x16x32_bf16(a1H, bL0, acc[1][0], 0, 0, 0); \
      acc[1][1] = __builtin_amdgcn_mfma_f32_16x16x32_bf16(a1H, bL1, acc[1][1], 0, 0, 0); \
    }                                                                          \
    if (LAST) {                                                                \
      _Pragma("unroll") for (int fr = 0; fr < 2; ++fr)                         \
      _Pragma("unroll") for (int fc = 0; fc < 2; ++fc) {                       \
        const float bias = fc ? bias1 : bias0;                                 \
        const int col = wn * 32 + fc * 16 + l16;                               \
        _Pragma("unroll") for (int i = 0; i < 4; ++i) {                        \
          const int row = r0 + wm * 32 + fr * 16 + g4 * 4 + i;                 \
          out[(size_t)row * 128 + col] = fmaxf(acc[fr][fc][i] + bias, 0.0f);   \
        }                                                                      \
      }                                                                        \
    } else {                                                                   \
      _Pragma("unroll") for (int fr = 0; fr < 2; ++fr)                         \
      _Pragma("unroll") for (int fc = 0; fc < 2; ++fc) {                       \
        const float bias = fc ? bias1 : bias0;                                 \
        _Pragma("unroll") for (int i = 0; i < 4; ++i) {                        \
          const float v = fmaxf(acc[fr][fc][i] + bias, 0.0f);                  \
          const uint32_t u  = __builtin_bit_cast(uint32_t, v);                 \
          const float    hi = __builtin_bit_cast(float, u & 0xFFFF0000u);      \
          const uint32_t ur = __builtin_bit_cast(uint32_t, v - hi);            \
          *(uint32_t*)(lds + (WRB) + eoff[fr][fc][i]) = perm_hihi(ur, u);      \
        }                                                                      \
      }                                                                        \
    }                                                                          \
    __syncthreads();                                                           \
  } while (0)

  for (int lp = 0; lp < 16; ++lp) {
    const int l0 = 2 * lp;
    LAYER_BODY(l0, B0, B1, LDS_ACT0, LDS_ACT1, l0 == NWL - 1, l0 + 1 < NWL);
    if (l0 + 1 < NWL) {
      const int l1 = l0 + 1;
      LAYER_BODY(l1, B1, B0, LDS_ACT1, LDS_ACT0, false, l1 + 1 < NWL);
    }
  }
#undef LAYER_BODY
}

// ---------------------------------------------------------------------------
extern "C" void kernel_launch(void* const* d_in, const int* in_sizes, int n_in,
                              void* d_out, int out_size, void* d_ws, size_t ws_size,
                              hipStream_t stream) {
  const float* x = (const float*)d_in[0];
  const float* W = (const float*)d_in[1];
  const float* M = (const float*)d_in[2];
  char*  wsW = (char*)d_ws;
  float* wsB = (float*)((char*)d_ws + WS_W_BYTES);
  float* out = (float*)d_out;

  (void)hipFuncSetAttribute((const void*)dag_mlp,
                            hipFuncAttributeMaxDynamicSharedMemorySize, LDS_TOTAL);

  hipLaunchKernelGGL(prep_weights, dim3(NWL * 4), dim3(512), 0, stream, W, M, wsW, wsB);
  hipLaunchKernelGGL(dag_mlp, dim3(256), dim3(512), LDS_TOTAL, stream, x, wsW, wsB, out);
}